// Round 4
// baseline (651.713 us; speedup 1.0000x reference)
//
#include <hip/hip_runtime.h>
#include <hip/hip_bf16.h>

typedef __attribute__((ext_vector_type(4))) float  f32x4;
typedef __attribute__((ext_vector_type(16))) float f32x16;
typedef __attribute__((ext_vector_type(8))) short  s16x8;
typedef __attribute__((ext_vector_type(4))) short  s16x4;

#define THR_  1.0e-4f   // LR * GAMMA
#define SC_   2.0e-3f   // 2 * LR

__device__ __forceinline__ unsigned short f2bf(float f) {
  union { __hip_bfloat16 b; unsigned short u; } cv;
  cv.b = __float2bfloat16(f);
  return cv.u;
}

__device__ __forceinline__ float sthr(float v) {
  return v - fmaxf(fminf(v, THR_), -THR_);   // v - clamp -> med3 + sub
}

// A-frag packing for 32x32x16 (A[row][k]): lane l holds row=(l&31), k=8*(l>>5)+j.
// ws layout (unsigned short elems):
// [0,65536)     Gpk: A-frags of (-2LR*G), G=W@W^T (symmetric). frag(kc 0..15, ntg 0..7):
//               elem j of lane l = -2LR*G[ntg*32+(l&31)][kc*16+8*(l>>5)+j]
// [65536,98304) Cpk: A-frags of (2LR*W). frag(kc 0..7, ntg 0..7):
//               elem j = 2LR*W[ntg*32+(l&31)][kc*16+8*(l>>5)+j]
// [98304,131072) Opk: A-frags of W^T. frag(kc 0..15, it 0..3):
//               elem j = W[kc*16+8*(l>>5)+j][it*32+(l&31)]
__global__ void sc_prep(const float* __restrict__ W, unsigned short* __restrict__ ws) {
  const int b = blockIdx.x;
  const int l = threadIdx.x;
  const int r = l & 31, h = l >> 5;
  if (b < 128) {                        // Gpk
    const int kc = b >> 3, ntg = b & 7;
    const int n = ntg * 32 + r;
    const int k0 = kc * 16 + 8 * h;
    float s[8];
    #pragma unroll
    for (int j = 0; j < 8; ++j) s[j] = 0.0f;
    for (int i = 0; i < 128; ++i) {
      const float wn = W[n * 128 + i];
      #pragma unroll
      for (int j = 0; j < 8; ++j) s[j] += W[(k0 + j) * 128 + i] * wn;
    }
    unsigned short* dst = ws + ((unsigned)b * 64u + l) * 8u;
    #pragma unroll
    for (int j = 0; j < 8; ++j) dst[j] = f2bf(-SC_ * s[j]);
  } else if (b < 192) {                 // Cpk
    const int bb = b - 128;
    const int kc = bb >> 3, ntg = bb & 7;
    const int n = ntg * 32 + r;
    const int k0 = kc * 16 + 8 * h;
    unsigned short* dst = ws + 65536u + ((unsigned)bb * 64u + l) * 8u;
    #pragma unroll
    for (int j = 0; j < 8; ++j) dst[j] = f2bf(SC_ * W[n * 128 + k0 + j]);
  } else {                              // Opk
    const int bb = b - 192;
    const int kc = bb >> 2, it = bb & 3;
    const int i = it * 32 + r;
    const int n0 = kc * 16 + 8 * h;
    unsigned short* dst = ws + 98304u + ((unsigned)bb * 64u + l) * 8u;
    #pragma unroll
    for (int j = 0; j < 8; ++j) dst[j] = f2bf(W[(n0 + j) * 128 + i]);
  }
}

// Swapped-operand structure: C'[n][m] = sum_k A[n][k]*B[k][m], A=G (symmetric,
// register-resident), B = x^T read from row-major x LDS via ds_read_b128.
// C' frag: m = lane&31 (batch row fixed/lane), n = (reg&3)+8*(reg>>2)+4*(lane>>5)
//  -> reg quads = 4 consecutive n = ds_write_b64 per quad. 32x32x16 MFMA.
// x LDS: [32 rows][256 bf16 + 4 pad], stride 520 B (130 dw, mod32=2 -> 2-way = free).
__global__ __launch_bounds__(256, 4) void sc_fused(
    const float* __restrict__ inp,
    const unsigned short* __restrict__ wsp,
    float* __restrict__ outp)
{
  __shared__ __align__(16) unsigned char lds[33280];  // XB0 [0,16640), XB1 [16640,33280)

  const int tid = threadIdx.x;
  const int l = tid & 63;
  const int w = tid >> 6;          // 0..3
  const int h = l >> 5;            // 0..1
  const int r31 = l & 31;
  const long row0 = (long)blockIdx.x * 32;

  // B-read base (x): row=l&31, k-col byte = kc*32 + h*16
  const int rB0 = r31 * 520 + h * 16;
  const int rB1 = rB0 + 16640;
  // x-write base: row=l&31, n = w*64 + nt*32 + q*8 + 4h (+s)
  const int wB0 = r31 * 520 + h * 8 + w * 128;
  const int wB1 = wB0 + 16640;

  // ---- stage inputs -> XB1 area, row-major bf16, stride 264 B ----
  #pragma unroll
  for (int rep = 0; rep < 4; ++rep) {
    const int flat = rep * 256 + tid;            // 0..1023 float4s
    const int rr = flat >> 5;                    // row 0..31
    const int c4 = flat & 31;
    const f32x4 v = *reinterpret_cast<const f32x4*>(inp + (row0 + rr) * 128 + c4 * 4);
    s16x4 p;
    p[0] = (short)f2bf(v[0]); p[1] = (short)f2bf(v[1]);
    p[2] = (short)f2bf(v[2]); p[3] = (short)f2bf(v[3]);
    *reinterpret_cast<s16x4*>(lds + 16640 + rr * 264 + c4 * 8) = p;
  }

  // ---- c-phase A-frags (2LR*W), ntg = w*2+nt ----
  s16x8 gfr[32];
  #pragma unroll
  for (int kc = 0; kc < 8; ++kc)
    #pragma unroll
    for (int nt = 0; nt < 2; ++nt)
      gfr[kc * 2 + nt] = *reinterpret_cast<const s16x8*>(
          wsp + 65536u + ((unsigned)(kc * 8 + w * 2 + nt) * 64u + l) * 8u);

  __syncthreads();

  // ---- c' = 2LR * W @ in^T ----
  f32x16 xacc[2], creg[2];
  #pragma unroll
  for (int nt = 0; nt < 2; ++nt)
    #pragma unroll
    for (int e = 0; e < 16; ++e) xacc[nt][e] = 0.0f;

  const int ib = 16640 + r31 * 264 + h * 16;
  #pragma unroll
  for (int kc = 0; kc < 8; ++kc) {
    const s16x8 b = *reinterpret_cast<const s16x8*>(lds + ib + kc * 32);
    __builtin_amdgcn_s_setprio(1);
    #pragma unroll
    for (int nt = 0; nt < 2; ++nt)
      xacc[nt] = __builtin_amdgcn_mfma_f32_32x32x16_bf16(gfr[kc * 2 + nt], b, xacc[nt], 0, 0, 0);
    __builtin_amdgcn_s_setprio(0);
  }

  // x1 = sthr(c); write x1 -> XB0 (b64 per reg-quad)
  #pragma unroll
  for (int nt = 0; nt < 2; ++nt) {
    creg[nt] = xacc[nt];
    #pragma unroll
    for (int q = 0; q < 4; ++q) {
      float f0 = sthr(xacc[nt][4 * q + 0]), f1 = sthr(xacc[nt][4 * q + 1]);
      float f2 = sthr(xacc[nt][4 * q + 2]), f3 = sthr(xacc[nt][4 * q + 3]);
      xacc[nt][4 * q + 0] = f0; xacc[nt][4 * q + 1] = f1;
      xacc[nt][4 * q + 2] = f2; xacc[nt][4 * q + 3] = f3;
      s16x4 p;
      p[0] = (short)f2bf(f0); p[1] = (short)f2bf(f1);
      p[2] = (short)f2bf(f2); p[3] = (short)f2bf(f3);
      *reinterpret_cast<s16x4*>(lds + wB0 + nt * 64 + q * 16) = p;
    }
  }

  // ---- step A-frags (-2LR*G), ntg = w*2+nt ----
  #pragma unroll
  for (int kc = 0; kc < 16; ++kc)
    #pragma unroll
    for (int nt = 0; nt < 2; ++nt)
      gfr[kc * 2 + nt] = *reinterpret_cast<const s16x8*>(
          wsp + ((unsigned)(kc * 8 + w * 2 + nt) * 64u + l) * 8u);

  // ---- one ISTA step: x <- sthr(x + c - 2LR*(G @ x^T)) ----
  auto STEP = [&](const int rb, const int wb) {
    __syncthreads();
    #pragma unroll
    for (int nt = 0; nt < 2; ++nt)
      #pragma unroll
      for (int e = 0; e < 16; ++e) xacc[nt][e] += creg[nt][e];
    #pragma unroll
    for (int kc = 0; kc < 16; ++kc) {
      const s16x8 b = *reinterpret_cast<const s16x8*>(lds + rb + kc * 32);
      __builtin_amdgcn_s_setprio(1);
      #pragma unroll
      for (int nt = 0; nt < 2; ++nt)
        xacc[nt] = __builtin_amdgcn_mfma_f32_32x32x16_bf16(gfr[kc * 2 + nt], b, xacc[nt], 0, 0, 0);
      __builtin_amdgcn_s_setprio(0);
    }
    #pragma unroll
    for (int nt = 0; nt < 2; ++nt)
      #pragma unroll
      for (int q = 0; q < 4; ++q) {
        float f0 = sthr(xacc[nt][4 * q + 0]), f1 = sthr(xacc[nt][4 * q + 1]);
        float f2 = sthr(xacc[nt][4 * q + 2]), f3 = sthr(xacc[nt][4 * q + 3]);
        xacc[nt][4 * q + 0] = f0; xacc[nt][4 * q + 1] = f1;
        xacc[nt][4 * q + 2] = f2; xacc[nt][4 * q + 3] = f3;
        s16x4 p;
        p[0] = (short)f2bf(f0); p[1] = (short)f2bf(f1);
        p[2] = (short)f2bf(f2); p[3] = (short)f2bf(f3);
        *reinterpret_cast<s16x4*>(lds + wb + nt * 64 + q * 16) = p;
      }
  };

  // 9 steps: x1 in XB0; x10 lands in XB1
  #pragma unroll 1
  for (int p = 0; p < 4; ++p) {
    STEP(rB0, wB1);
    STEP(rB1, wB0);
  }
  STEP(rB0, wB1);

  // ---- out^T = W^T @ x^T ; wave w owns out cols [w*32, w*32+32) ----
  __syncthreads();
  #pragma unroll
  for (int kc = 0; kc < 16; ++kc)
    gfr[kc] = *reinterpret_cast<const s16x8*>(
        wsp + 98304u + ((unsigned)(kc * 4 + w) * 64u + l) * 8u);
  f32x16 oacc;
  #pragma unroll
  for (int e = 0; e < 16; ++e) oacc[e] = 0.0f;
  #pragma unroll
  for (int kc = 0; kc < 16; ++kc) {
    const s16x8 b = *reinterpret_cast<const s16x8*>(lds + rB1 + kc * 32);
    __builtin_amdgcn_s_setprio(1);
    oacc = __builtin_amdgcn_mfma_f32_32x32x16_bf16(gfr[kc], b, oacc, 0, 0, 0);
    __builtin_amdgcn_s_setprio(0);
  }
  // stage out f32 to XB0: out[m][i], m=l&31, i = w*32 + q*8 + 4h (+s); stride 520
  const int ob = r31 * 520 + h * 16 + w * 128;
  #pragma unroll
  for (int q = 0; q < 4; ++q) {
    f32x4 p;
    p[0] = oacc[4 * q + 0]; p[1] = oacc[4 * q + 1];
    p[2] = oacc[4 * q + 2]; p[3] = oacc[4 * q + 3];
    *reinterpret_cast<f32x4*>(lds + ob + q * 32) = p;
  }
  __syncthreads();
  // coalesced copy 32 rows x 128 f32 -> global
  #pragma unroll
  for (int rep = 0; rep < 4; ++rep) {
    const int flat = rep * 256 + tid;
    const int rr = flat >> 5;
    const int c4 = flat & 31;
    const f32x4 v = *reinterpret_cast<const f32x4*>(lds + rr * 520 + c4 * 16);
    *reinterpret_cast<f32x4*>(outp + (row0 + rr) * 128 + c4 * 4) = v;
  }
}

extern "C" void kernel_launch(void* const* d_in, const int* in_sizes, int n_in,
                              void* d_out, int out_size, void* d_ws, size_t ws_size,
                              hipStream_t stream) {
  const float* inp = (const float*)d_in[0];
  const float* W   = (const float*)d_in[1];
  unsigned short* ws = (unsigned short*)d_ws;   // needs 256 KiB
  float* outp = (float*)d_out;
  const int B = in_sizes[0] / 128;              // 131072
  sc_prep<<<256, 64, 0, stream>>>(W, ws);
  sc_fused<<<B / 32, 256, 0, stream>>>(inp, ws, outp);
}

// Round 5
// 184.631 us; speedup vs baseline: 3.5298x; 3.5298x over previous
//
#include <hip/hip_runtime.h>
#include <hip/hip_bf16.h>

typedef __attribute__((ext_vector_type(4))) float  f32x4;
typedef __attribute__((ext_vector_type(16))) float f32x16;
typedef __attribute__((ext_vector_type(8))) short  s16x8;
typedef __attribute__((ext_vector_type(4))) short  s16x4;

#define THR_  1.0e-4f   // LR * GAMMA
#define SC_   2.0e-3f   // 2 * LR

__device__ __forceinline__ unsigned short f2bf(float f) {
  union { __hip_bfloat16 b; unsigned short u; } cv;
  cv.b = __float2bfloat16(f);
  return cv.u;
}

__device__ __forceinline__ float sthr(float v) {
  return v - fmaxf(fminf(v, THR_), -THR_);   // v - clamp -> med3 + sub
}

// A-frag packing for 32x32x16 (A[row][k]): lane l holds row=(l&31), k=8*(l>>5)+j.
// ws layout (unsigned short elems):
// [0,65536)     Gpk: A-frags of (-2LR*G), G=W@W^T (symmetric). frag(kc 0..15, ntg 0..7):
//               elem j of lane l = -2LR*G[ntg*32+(l&31)][kc*16+8*(l>>5)+j]
// [65536,98304) Cpk: A-frags of (2LR*W). frag(kc 0..7, ntg 0..7):
//               elem j = 2LR*W[ntg*32+(l&31)][kc*16+8*(l>>5)+j]
// [98304,131072) Opk: A-frags of W^T. frag(kc 0..15, it 0..3):
//               elem j = W[kc*16+8*(l>>5)+j][it*32+(l&31)]
__global__ void sc_prep(const float* __restrict__ W, unsigned short* __restrict__ ws) {
  const int b = blockIdx.x;
  const int l = threadIdx.x;
  const int r = l & 31, h = l >> 5;
  if (b < 128) {                        // Gpk
    const int kc = b >> 3, ntg = b & 7;
    const int n = ntg * 32 + r;
    const int k0 = kc * 16 + 8 * h;
    float s[8];
    #pragma unroll
    for (int j = 0; j < 8; ++j) s[j] = 0.0f;
    for (int i = 0; i < 128; ++i) {
      const float wn = W[n * 128 + i];
      #pragma unroll
      for (int j = 0; j < 8; ++j) s[j] += W[(k0 + j) * 128 + i] * wn;
    }
    unsigned short* dst = ws + ((unsigned)b * 64u + l) * 8u;
    #pragma unroll
    for (int j = 0; j < 8; ++j) dst[j] = f2bf(-SC_ * s[j]);
  } else if (b < 192) {                 // Cpk
    const int bb = b - 128;
    const int kc = bb >> 3, ntg = bb & 7;
    const int n = ntg * 32 + r;
    const int k0 = kc * 16 + 8 * h;
    unsigned short* dst = ws + 65536u + ((unsigned)bb * 64u + l) * 8u;
    #pragma unroll
    for (int j = 0; j < 8; ++j) dst[j] = f2bf(SC_ * W[n * 128 + k0 + j]);
  } else {                              // Opk
    const int bb = b - 192;
    const int kc = bb >> 2, it = bb & 3;
    const int i = it * 32 + r;
    const int n0 = kc * 16 + 8 * h;
    unsigned short* dst = ws + 98304u + ((unsigned)bb * 64u + l) * 8u;
    #pragma unroll
    for (int j = 0; j < 8; ++j) dst[j] = f2bf(W[(n0 + j) * 128 + i]);
  }
}

// Swapped-operand structure: C'[n][m] = sum_k A[n][k]*B[k][m], A=G (symmetric,
// register-resident), B = x^T read from row-major x LDS via ds_read_b128.
// C' frag: m = lane&31 (batch row fixed/lane), n = (reg&3)+8*(reg>>2)+4*(lane>>5)
//  -> reg quads = 4 consecutive n = ds_write_b64 per quad. 32x32x16 MFMA.
// x LDS: [32 rows][256 bf16 + 4 pad], stride 520 B (conflict-measured ok: 5.2e5).
// NOTE: working set ~215 VGPR -> ONLY __launch_bounds__(256,2) is legal here.
// (256,4) caps the allocator at 128 VGPR and spills ~2.5 GB to scratch (R2/R4).
__global__ __launch_bounds__(256, 2) void sc_fused(
    const float* __restrict__ inp,
    const unsigned short* __restrict__ wsp,
    float* __restrict__ outp)
{
  __shared__ __align__(16) unsigned char lds[33280];  // XB0 [0,16640), XB1 [16640,33280)

  const int tid = threadIdx.x;
  const int l = tid & 63;
  const int w = tid >> 6;          // 0..3
  const int h = l >> 5;            // 0..1
  const int r31 = l & 31;
  const long row0 = (long)blockIdx.x * 32;

  // B-read base (x): row=l&31, k-col byte = kc*32 + h*16
  const int rB0 = r31 * 520 + h * 16;
  const int rB1 = rB0 + 16640;
  // x-write base: row=l&31, n = w*64 + nt*32 + q*8 + 4h (+s)
  const int wB0 = r31 * 520 + h * 8 + w * 128;
  const int wB1 = wB0 + 16640;

  // ---- stage inputs -> XB1 area, row-major bf16, stride 264 B ----
  #pragma unroll
  for (int rep = 0; rep < 4; ++rep) {
    const int flat = rep * 256 + tid;            // 0..1023 float4s
    const int rr = flat >> 5;                    // row 0..31
    const int c4 = flat & 31;
    const f32x4 v = *reinterpret_cast<const f32x4*>(inp + (row0 + rr) * 128 + c4 * 4);
    s16x4 p;
    p[0] = (short)f2bf(v[0]); p[1] = (short)f2bf(v[1]);
    p[2] = (short)f2bf(v[2]); p[3] = (short)f2bf(v[3]);
    *reinterpret_cast<s16x4*>(lds + 16640 + rr * 264 + c4 * 8) = p;
  }

  // ---- c-phase A-frags (2LR*W), ntg = w*2+nt ----
  s16x8 gfr[32];
  #pragma unroll
  for (int kc = 0; kc < 8; ++kc)
    #pragma unroll
    for (int nt = 0; nt < 2; ++nt)
      gfr[kc * 2 + nt] = *reinterpret_cast<const s16x8*>(
          wsp + 65536u + ((unsigned)(kc * 8 + w * 2 + nt) * 64u + l) * 8u);

  __syncthreads();

  // ---- c' = 2LR * W @ in^T ----
  f32x16 xacc[2], creg[2];
  #pragma unroll
  for (int nt = 0; nt < 2; ++nt)
    #pragma unroll
    for (int e = 0; e < 16; ++e) xacc[nt][e] = 0.0f;

  const int ib = 16640 + r31 * 264 + h * 16;
  #pragma unroll
  for (int kc = 0; kc < 8; ++kc) {
    const s16x8 b = *reinterpret_cast<const s16x8*>(lds + ib + kc * 32);
    __builtin_amdgcn_s_setprio(1);
    #pragma unroll
    for (int nt = 0; nt < 2; ++nt)
      xacc[nt] = __builtin_amdgcn_mfma_f32_32x32x16_bf16(gfr[kc * 2 + nt], b, xacc[nt], 0, 0, 0);
    __builtin_amdgcn_s_setprio(0);
  }

  // x1 = sthr(c); write x1 -> XB0 (b64 per reg-quad)
  #pragma unroll
  for (int nt = 0; nt < 2; ++nt) {
    creg[nt] = xacc[nt];
    #pragma unroll
    for (int q = 0; q < 4; ++q) {
      float f0 = sthr(xacc[nt][4 * q + 0]), f1 = sthr(xacc[nt][4 * q + 1]);
      float f2 = sthr(xacc[nt][4 * q + 2]), f3 = sthr(xacc[nt][4 * q + 3]);
      xacc[nt][4 * q + 0] = f0; xacc[nt][4 * q + 1] = f1;
      xacc[nt][4 * q + 2] = f2; xacc[nt][4 * q + 3] = f3;
      s16x4 p;
      p[0] = (short)f2bf(f0); p[1] = (short)f2bf(f1);
      p[2] = (short)f2bf(f2); p[3] = (short)f2bf(f3);
      *reinterpret_cast<s16x4*>(lds + wB0 + nt * 64 + q * 16) = p;
    }
  }

  // ---- step A-frags (-2LR*G), ntg = w*2+nt ----
  #pragma unroll
  for (int kc = 0; kc < 16; ++kc)
    #pragma unroll
    for (int nt = 0; nt < 2; ++nt)
      gfr[kc * 2 + nt] = *reinterpret_cast<const s16x8*>(
          wsp + ((unsigned)(kc * 8 + w * 2 + nt) * 64u + l) * 8u);

  // ---- one ISTA step: x <- sthr(x + c - 2LR*(G @ x^T)) ----
  auto STEP = [&](const int rb, const int wb) {
    __syncthreads();
    #pragma unroll
    for (int nt = 0; nt < 2; ++nt)
      #pragma unroll
      for (int e = 0; e < 16; ++e) xacc[nt][e] += creg[nt][e];
    #pragma unroll
    for (int kc = 0; kc < 16; ++kc) {
      const s16x8 b = *reinterpret_cast<const s16x8*>(lds + rb + kc * 32);
      __builtin_amdgcn_s_setprio(1);
      #pragma unroll
      for (int nt = 0; nt < 2; ++nt)
        xacc[nt] = __builtin_amdgcn_mfma_f32_32x32x16_bf16(gfr[kc * 2 + nt], b, xacc[nt], 0, 0, 0);
      __builtin_amdgcn_s_setprio(0);
    }
    #pragma unroll
    for (int nt = 0; nt < 2; ++nt)
      #pragma unroll
      for (int q = 0; q < 4; ++q) {
        float f0 = sthr(xacc[nt][4 * q + 0]), f1 = sthr(xacc[nt][4 * q + 1]);
        float f2 = sthr(xacc[nt][4 * q + 2]), f3 = sthr(xacc[nt][4 * q + 3]);
        xacc[nt][4 * q + 0] = f0; xacc[nt][4 * q + 1] = f1;
        xacc[nt][4 * q + 2] = f2; xacc[nt][4 * q + 3] = f3;
        s16x4 p;
        p[0] = (short)f2bf(f0); p[1] = (short)f2bf(f1);
        p[2] = (short)f2bf(f2); p[3] = (short)f2bf(f3);
        *reinterpret_cast<s16x4*>(lds + wb + nt * 64 + q * 16) = p;
      }
  };

  // 9 steps: x1 in XB0; x10 lands in XB1
  #pragma unroll 1
  for (int p = 0; p < 4; ++p) {
    STEP(rB0, wB1);
    STEP(rB1, wB0);
  }
  STEP(rB0, wB1);

  // ---- out^T = W^T @ x^T ; wave w owns out cols [w*32, w*32+32) ----
  __syncthreads();
  #pragma unroll
  for (int kc = 0; kc < 16; ++kc)
    gfr[kc] = *reinterpret_cast<const s16x8*>(
        wsp + 98304u + ((unsigned)(kc * 4 + w) * 64u + l) * 8u);
  f32x16 oacc;
  #pragma unroll
  for (int e = 0; e < 16; ++e) oacc[e] = 0.0f;
  #pragma unroll
  for (int kc = 0; kc < 16; ++kc) {
    const s16x8 b = *reinterpret_cast<const s16x8*>(lds + rB1 + kc * 32);
    __builtin_amdgcn_s_setprio(1);
    oacc = __builtin_amdgcn_mfma_f32_32x32x16_bf16(gfr[kc], b, oacc, 0, 0, 0);
    __builtin_amdgcn_s_setprio(0);
  }
  // stage out f32 to XB0: out[m][i], m=l&31, i = w*32 + q*8 + 4h (+s); stride 520
  const int ob = r31 * 520 + h * 16 + w * 128;
  #pragma unroll
  for (int q = 0; q < 4; ++q) {
    f32x4 p;
    p[0] = oacc[4 * q + 0]; p[1] = oacc[4 * q + 1];
    p[2] = oacc[4 * q + 2]; p[3] = oacc[4 * q + 3];
    *reinterpret_cast<f32x4*>(lds + ob + q * 32) = p;
  }
  __syncthreads();
  // coalesced copy 32 rows x 128 f32 -> global
  #pragma unroll
  for (int rep = 0; rep < 4; ++rep) {
    const int flat = rep * 256 + tid;
    const int rr = flat >> 5;
    const int c4 = flat & 31;
    const f32x4 v = *reinterpret_cast<const f32x4*>(lds + rr * 520 + c4 * 16);
    *reinterpret_cast<f32x4*>(outp + (row0 + rr) * 128 + c4 * 4) = v;
  }
}

extern "C" void kernel_launch(void* const* d_in, const int* in_sizes, int n_in,
                              void* d_out, int out_size, void* d_ws, size_t ws_size,
                              hipStream_t stream) {
  const float* inp = (const float*)d_in[0];
  const float* W   = (const float*)d_in[1];
  unsigned short* ws = (unsigned short*)d_ws;   // needs 256 KiB
  float* outp = (float*)d_out;
  const int B = in_sizes[0] / 128;              // 131072
  sc_prep<<<256, 64, 0, stream>>>(W, ws);
  sc_fused<<<B / 32, 256, 0, stream>>>(inp, ws, outp);
}

// Round 6
// 179.667 us; speedup vs baseline: 3.6273x; 1.0276x over previous
//
#include <hip/hip_runtime.h>
#include <hip/hip_bf16.h>

typedef __attribute__((ext_vector_type(4))) float  f32x4;
typedef __attribute__((ext_vector_type(16))) float f32x16;
typedef __attribute__((ext_vector_type(8))) short  s16x8;
typedef __attribute__((ext_vector_type(4))) short  s16x4;

#define THR_  1.0e-4f   // LR * GAMMA
#define SC_   2.0e-3f   // 2 * LR

__device__ __forceinline__ unsigned short f2bf(float f) {
  union { __hip_bfloat16 b; unsigned short u; } cv;
  cv.b = __float2bfloat16(f);
  return cv.u;
}

__device__ __forceinline__ float sthr(float v) {
  return v - fmaxf(fminf(v, THR_), -THR_);   // v - clamp -> med3 + sub
}

// A-frag packing for 32x32x16 (A[row][k]): lane l holds row=(l&31), k=8*(l>>5)+j.
// ws layout (unsigned short elems):
// [0,65536)     Gpk: A-frags of (-2LR*G), G=W@W^T (symmetric). frag(kc 0..15, ntg 0..7)
// [65536,98304) Cpk: A-frags of (2LR*W). frag(kc 0..7, ntg 0..7)
// [98304,131072) Opk: A-frags of W^T. frag(kc 0..15, it 0..3)
__global__ void sc_prep(const float* __restrict__ W, unsigned short* __restrict__ ws) {
  const int b = blockIdx.x;
  const int l = threadIdx.x;
  const int r = l & 31, h = l >> 5;
  if (b < 128) {                        // Gpk
    const int kc = b >> 3, ntg = b & 7;
    const int n = ntg * 32 + r;
    const int k0 = kc * 16 + 8 * h;
    float s[8];
    #pragma unroll
    for (int j = 0; j < 8; ++j) s[j] = 0.0f;
    for (int i = 0; i < 128; ++i) {
      const float wn = W[n * 128 + i];
      #pragma unroll
      for (int j = 0; j < 8; ++j) s[j] += W[(k0 + j) * 128 + i] * wn;
    }
    unsigned short* dst = ws + ((unsigned)b * 64u + l) * 8u;
    #pragma unroll
    for (int j = 0; j < 8; ++j) dst[j] = f2bf(-SC_ * s[j]);
  } else if (b < 192) {                 // Cpk
    const int bb = b - 128;
    const int kc = bb >> 3, ntg = bb & 7;
    const int n = ntg * 32 + r;
    const int k0 = kc * 16 + 8 * h;
    unsigned short* dst = ws + 65536u + ((unsigned)bb * 64u + l) * 8u;
    #pragma unroll
    for (int j = 0; j < 8; ++j) dst[j] = f2bf(SC_ * W[n * 128 + k0 + j]);
  } else {                              // Opk
    const int bb = b - 192;
    const int kc = bb >> 2, it = bb & 3;
    const int i = it * 32 + r;
    const int n0 = kc * 16 + 8 * h;
    unsigned short* dst = ws + 98304u + ((unsigned)bb * 64u + l) * 8u;
    #pragma unroll
    for (int j = 0; j < 8; ++j) dst[j] = f2bf(W[(n0 + j) * 128 + i]);
  }
}

// Swapped-operand 32x32x16 structure (R5-validated). This round:
//  - K-split accumulators accA (kc 0-7) / accB (kc 8-15): 4 independent MFMA
//    chains, ds_reads paired -> issue never waits on a 16-deep dependent chain.
//  - acc pre-init hoist: writeback immediately sets accA = x_new + creg,
//    accB = 0 BEFORE the barrier; post-barrier goes straight to ds_read->MFMA.
//  - anti-phase stagger: co-resident pair is (b, b+256) at first fill ->
//    odd (b>>8) blocks sleep ~1250 cyc once so step phases interleave on the CU.
// NOTE: working set ~215 unified regs -> ONLY __launch_bounds__(256,2) is legal
// ((256,4) caps allocator at 64 VGPR and spills ~2.5 GB to scratch: R2/R4).
__global__ __launch_bounds__(256, 2) void sc_fused(
    const float* __restrict__ inp,
    const unsigned short* __restrict__ wsp,
    float* __restrict__ outp)
{
  __shared__ __align__(16) unsigned char lds[33280];  // XB0 [0,16640), XB1/INB [16640,33280)

  if ((blockIdx.x >> 8) & 1) {          // anti-phase stagger (~1250 cyc, one-time)
    __builtin_amdgcn_s_sleep(15);
    __builtin_amdgcn_s_sleep(5);
  }

  const int tid = threadIdx.x;
  const int l = tid & 63;
  const int w = tid >> 6;          // 0..3
  const int h = l >> 5;            // 0..1
  const int r31 = l & 31;
  const long row0 = (long)blockIdx.x * 32;

  // B-read base (x): row=l&31, k-col byte = kc*32 + h*16
  const int rB0 = r31 * 520 + h * 16;
  const int rB1 = rB0 + 16640;
  // x-write base: row=l&31, n = w*64 + nt*32 + q*8 + 4h (+s)
  const int wB0 = r31 * 520 + h * 8 + w * 128;
  const int wB1 = wB0 + 16640;

  // ---- stage inputs -> XB1 area, row-major bf16, stride 264 B ----
  #pragma unroll
  for (int rep = 0; rep < 4; ++rep) {
    const int flat = rep * 256 + tid;            // 0..1023 float4s
    const int rr = flat >> 5;                    // row 0..31
    const int c4 = flat & 31;
    const f32x4 v = *reinterpret_cast<const f32x4*>(inp + (row0 + rr) * 128 + c4 * 4);
    s16x4 p;
    p[0] = (short)f2bf(v[0]); p[1] = (short)f2bf(v[1]);
    p[2] = (short)f2bf(v[2]); p[3] = (short)f2bf(v[3]);
    *reinterpret_cast<s16x4*>(lds + 16640 + rr * 264 + c4 * 8) = p;
  }

  // ---- c-phase A-frags (2LR*W), ntg = w*2+nt ----
  s16x8 gfr[32];
  #pragma unroll
  for (int kc = 0; kc < 8; ++kc)
    #pragma unroll
    for (int nt = 0; nt < 2; ++nt)
      gfr[kc * 2 + nt] = *reinterpret_cast<const s16x8*>(
          wsp + 65536u + ((unsigned)(kc * 8 + w * 2 + nt) * 64u + l) * 8u);

  __syncthreads();

  // ---- c' = 2LR * W @ in^T  (K=128 split: kc 0-3 -> accA, 4-7 -> accB) ----
  f32x16 accA[2], accB[2], creg[2];
  #pragma unroll
  for (int nt = 0; nt < 2; ++nt)
    #pragma unroll
    for (int e = 0; e < 16; ++e) { accA[nt][e] = 0.0f; accB[nt][e] = 0.0f; }

  const int ib = 16640 + r31 * 264 + h * 16;
  #pragma unroll
  for (int kc = 0; kc < 4; ++kc) {
    const s16x8 bA = *reinterpret_cast<const s16x8*>(lds + ib + kc * 32);
    const s16x8 bB = *reinterpret_cast<const s16x8*>(lds + ib + (kc + 4) * 32);
    __builtin_amdgcn_s_setprio(1);
    #pragma unroll
    for (int nt = 0; nt < 2; ++nt)
      accA[nt] = __builtin_amdgcn_mfma_f32_32x32x16_bf16(gfr[kc * 2 + nt], bA, accA[nt], 0, 0, 0);
    #pragma unroll
    for (int nt = 0; nt < 2; ++nt)
      accB[nt] = __builtin_amdgcn_mfma_f32_32x32x16_bf16(gfr[(kc + 4) * 2 + nt], bB, accB[nt], 0, 0, 0);
    __builtin_amdgcn_s_setprio(0);
  }

  // x1 = sthr(c); write x1 -> XB0; pre-init accA = x1 + creg, accB = 0
  #pragma unroll
  for (int nt = 0; nt < 2; ++nt)
    #pragma unroll
    for (int q = 0; q < 4; ++q) {
      float f0 = accA[nt][4 * q + 0] + accB[nt][4 * q + 0];
      float f1 = accA[nt][4 * q + 1] + accB[nt][4 * q + 1];
      float f2 = accA[nt][4 * q + 2] + accB[nt][4 * q + 2];
      float f3 = accA[nt][4 * q + 3] + accB[nt][4 * q + 3];
      creg[nt][4 * q + 0] = f0; creg[nt][4 * q + 1] = f1;
      creg[nt][4 * q + 2] = f2; creg[nt][4 * q + 3] = f3;
      f0 = sthr(f0); f1 = sthr(f1); f2 = sthr(f2); f3 = sthr(f3);
      s16x4 p;
      p[0] = (short)f2bf(f0); p[1] = (short)f2bf(f1);
      p[2] = (short)f2bf(f2); p[3] = (short)f2bf(f3);
      *reinterpret_cast<s16x4*>(lds + wB0 + nt * 64 + q * 16) = p;
      accA[nt][4 * q + 0] = f0 + creg[nt][4 * q + 0];
      accA[nt][4 * q + 1] = f1 + creg[nt][4 * q + 1];
      accA[nt][4 * q + 2] = f2 + creg[nt][4 * q + 2];
      accA[nt][4 * q + 3] = f3 + creg[nt][4 * q + 3];
      accB[nt][4 * q + 0] = 0.0f; accB[nt][4 * q + 1] = 0.0f;
      accB[nt][4 * q + 2] = 0.0f; accB[nt][4 * q + 3] = 0.0f;
    }

  // ---- step A-frags (-2LR*G), ntg = w*2+nt ----
  #pragma unroll
  for (int kc = 0; kc < 16; ++kc)
    #pragma unroll
    for (int nt = 0; nt < 2; ++nt)
      gfr[kc * 2 + nt] = *reinterpret_cast<const s16x8*>(
          wsp + ((unsigned)(kc * 8 + w * 2 + nt) * 64u + l) * 8u);

  // ---- one ISTA step. Entry invariant: accA = x + creg, accB = 0, x in rb.
  //      Exit: x_new written to wb, accA/accB pre-initialized for next step.
  auto STEP = [&](const int rb, const int wb) {
    __syncthreads();
    #pragma unroll
    for (int kc = 0; kc < 8; ++kc) {
      const s16x8 bA = *reinterpret_cast<const s16x8*>(lds + rb + kc * 32);
      const s16x8 bB = *reinterpret_cast<const s16x8*>(lds + rb + (kc + 8) * 32);
      __builtin_amdgcn_s_setprio(1);
      #pragma unroll
      for (int nt = 0; nt < 2; ++nt)
        accA[nt] = __builtin_amdgcn_mfma_f32_32x32x16_bf16(gfr[kc * 2 + nt], bA, accA[nt], 0, 0, 0);
      #pragma unroll
      for (int nt = 0; nt < 2; ++nt)
        accB[nt] = __builtin_amdgcn_mfma_f32_32x32x16_bf16(gfr[(kc + 8) * 2 + nt], bB, accB[nt], 0, 0, 0);
      __builtin_amdgcn_s_setprio(0);
    }
    #pragma unroll
    for (int nt = 0; nt < 2; ++nt)
      #pragma unroll
      for (int q = 0; q < 4; ++q) {
        float f0 = sthr(accA[nt][4 * q + 0] + accB[nt][4 * q + 0]);
        float f1 = sthr(accA[nt][4 * q + 1] + accB[nt][4 * q + 1]);
        float f2 = sthr(accA[nt][4 * q + 2] + accB[nt][4 * q + 2]);
        float f3 = sthr(accA[nt][4 * q + 3] + accB[nt][4 * q + 3]);
        s16x4 p;
        p[0] = (short)f2bf(f0); p[1] = (short)f2bf(f1);
        p[2] = (short)f2bf(f2); p[3] = (short)f2bf(f3);
        *reinterpret_cast<s16x4*>(lds + wb + nt * 64 + q * 16) = p;
        accA[nt][4 * q + 0] = f0 + creg[nt][4 * q + 0];
        accA[nt][4 * q + 1] = f1 + creg[nt][4 * q + 1];
        accA[nt][4 * q + 2] = f2 + creg[nt][4 * q + 2];
        accA[nt][4 * q + 3] = f3 + creg[nt][4 * q + 3];
        accB[nt][4 * q + 0] = 0.0f; accB[nt][4 * q + 1] = 0.0f;
        accB[nt][4 * q + 2] = 0.0f; accB[nt][4 * q + 3] = 0.0f;
      }
  };

  // 9 steps: x1 in XB0; x10 lands in XB1
  #pragma unroll 1
  for (int p = 0; p < 4; ++p) {
    STEP(rB0, wB1);
    STEP(rB1, wB0);
  }
  STEP(rB0, wB1);

  // ---- out^T = W^T @ x^T ; wave w owns out cols [w*32, w*32+32) ----
  __syncthreads();
  #pragma unroll
  for (int kc = 0; kc < 16; ++kc)
    gfr[kc] = *reinterpret_cast<const s16x8*>(
        wsp + 98304u + ((unsigned)(kc * 4 + w) * 64u + l) * 8u);
  f32x16 oA, oB;
  #pragma unroll
  for (int e = 0; e < 16; ++e) { oA[e] = 0.0f; oB[e] = 0.0f; }
  #pragma unroll
  for (int kc = 0; kc < 8; ++kc) {
    const s16x8 bA = *reinterpret_cast<const s16x8*>(lds + rB1 + kc * 32);
    const s16x8 bB = *reinterpret_cast<const s16x8*>(lds + rB1 + (kc + 8) * 32);
    __builtin_amdgcn_s_setprio(1);
    oA = __builtin_amdgcn_mfma_f32_32x32x16_bf16(gfr[kc], bA, oA, 0, 0, 0);
    oB = __builtin_amdgcn_mfma_f32_32x32x16_bf16(gfr[kc + 8], bB, oB, 0, 0, 0);
    __builtin_amdgcn_s_setprio(0);
  }
  // stage out f32 to XB0: out[m][i], m=l&31, i = w*32 + q*8 + 4h (+s); stride 520
  const int ob = r31 * 520 + h * 16 + w * 128;
  #pragma unroll
  for (int q = 0; q < 4; ++q) {
    f32x4 p;
    p[0] = oA[4 * q + 0] + oB[4 * q + 0]; p[1] = oA[4 * q + 1] + oB[4 * q + 1];
    p[2] = oA[4 * q + 2] + oB[4 * q + 2]; p[3] = oA[4 * q + 3] + oB[4 * q + 3];
    *reinterpret_cast<f32x4*>(lds + ob + q * 32) = p;
  }
  __syncthreads();
  // coalesced copy 32 rows x 128 f32 -> global
  #pragma unroll
  for (int rep = 0; rep < 4; ++rep) {
    const int flat = rep * 256 + tid;
    const int rr = flat >> 5;
    const int c4 = flat & 31;
    const f32x4 v = *reinterpret_cast<const f32x4*>(lds + rr * 520 + c4 * 16);
    *reinterpret_cast<f32x4*>(outp + (row0 + rr) * 128 + c4 * 4) = v;
  }
}

extern "C" void kernel_launch(void* const* d_in, const int* in_sizes, int n_in,
                              void* d_out, int out_size, void* d_ws, size_t ws_size,
                              hipStream_t stream) {
  const float* inp = (const float*)d_in[0];
  const float* W   = (const float*)d_in[1];
  unsigned short* ws = (unsigned short*)d_ws;   // needs 256 KiB
  float* outp = (float*)d_out;
  const int B = in_sizes[0] / 128;              // 131072
  sc_prep<<<256, 64, 0, stream>>>(W, ws);
  sc_fused<<<B / 32, 256, 0, stream>>>(inp, ws, outp);
}